// Round 8
// baseline (251.058 us; speedup 1.0000x reference)
//
#include <hip/hip_runtime.h>

typedef unsigned short u16;
typedef __bf16 bf16x8 __attribute__((ext_vector_type(8)));
typedef float f32x4 __attribute__((ext_vector_type(4)));

// ---------- bf16 <-> f32 helpers (RNE) ----------
__device__ __forceinline__ u16 f2bf(float f) {
    union { float f; unsigned int u; } v; v.f = f;
    unsigned int u = v.u;
    return (u16)((u + 0x7FFFu + ((u >> 16) & 1u)) >> 16);
}

// ---------- async global->LDS, 16B per lane ----------
__device__ __forceinline__ void load_lds16(const void* g, void* l) {
    __builtin_amdgcn_global_load_lds(
        (const __attribute__((address_space(1))) unsigned int*)g,
        (__attribute__((address_space(3))) unsigned int*)l,
        16, 0, 0);
}

// MODE2 classes, LPT (heaviest-first) order. Work in BK64 K-steps:
// m4 full=20, m7 halves=16+16, m3 full=16, m6 halves=14+14,
// m5 halves=12+12, m2 full=12, m1=8, m0=4. kh==2 -> full tile.
__constant__ unsigned char cls2_m[11] = {4,7,7,3,6,6,5,5,2,1,0};
__constant__ unsigned char cls2_h[11] = {2,0,1,2,0,1,0,1,2,2,2};

// ---------------------------------------------------------------
// fused prep: 0..8191 cast x fp32->bf16; 8192..11263 transpose W;
// 11264..11295 zero rowsum (8192 floats).
// ---------------------------------------------------------------
__global__ void __launch_bounds__(256) prep_kernel(
    const float4* __restrict__ X, u16* __restrict__ xb,
    const float* __restrict__ Wq, const float* __restrict__ Wk,
    const float* __restrict__ Wv,
    u16* __restrict__ Oq, u16* __restrict__ Ok, u16* __restrict__ Ov,
    float* __restrict__ rowsum) {
    __shared__ float tile[32][33];
    const int bid = blockIdx.x, tid = threadIdx.x;
    if (bid < 8192) {
        int idx = bid * 256 + tid;
        float4 v = X[idx];
        ushort4 o;
        o.x = f2bf(v.x); o.y = f2bf(v.y); o.z = f2bf(v.z); o.w = f2bf(v.w);
        *(ushort4*)(xb + (size_t)idx * 4) = o;
    } else if (bid < 11264) {
        int id = bid - 8192;
        int zz = id >> 10;
        const float* W = (zz == 0) ? Wq : (zz == 1) ? Wk : Wv;
        u16* O = (zz == 0) ? Oq : (zz == 1) ? Ok : Ov;
        int n0 = (id & 31) * 32, k0 = ((id >> 5) & 31) * 32;
        int tx = tid & 31, ty = tid >> 5;
        #pragma unroll
        for (int j = 0; j < 32; j += 8)
            tile[ty + j][tx] = W[(size_t)(k0 + ty + j) * 1024 + n0 + tx];
        __syncthreads();
        #pragma unroll
        for (int j = 0; j < 32; j += 8)
            O[(size_t)(n0 + ty + j) * 1024 + k0 + tx] = f2bf(tile[tx][ty + j]);
    } else {
        rowsum[(bid - 11264) * 256 + tid] = 0.f;
    }
}

// ---------------------------------------------------------------
// combine: out[z][1280+r][:] = (out + P1) * inv(rowsum) for the
// MODE2 split-K rows (mtiles 5..7 -> rows 1280..2047 per batch).
// 3072 blocks x 256 threads, one float4 per lane.
// ---------------------------------------------------------------
__global__ void __launch_bounds__(256) combine_kernel(
    const float4* __restrict__ P1, const float* __restrict__ rowsum,
    float4* __restrict__ out) {
    int b = blockIdx.x;                        // 0..3071
    int z = b / 768;
    int lb = b - z * 768;
    int j = lb * 256 + threadIdx.x;            // 0..196607 f4 within z
    int rl = j >> 8;                           // 256 f4 per row -> 0..767
    float inv = 1.0f / rowsum[z * 2048 + 1280 + rl];
    size_t oi = (size_t)z * 524288 + 327680 + j;   // rows 1280.. of out[z]
    float4 a = out[oi];
    float4 p = P1[(size_t)z * 196608 + j];
    a.x = (a.x + p.x) * inv;
    a.y = (a.y + p.y) * inv;
    a.z = (a.z + p.z) * inv;
    a.w = (a.w + p.w) * inv;
    out[oi] = a;
}

// ---------------------------------------------------------------
// Pipelined NT bf16 GEMM. BM=256, BN=128, BK=64. 512 threads = 8
// waves (4x2); per-wave 64x64 (acc[4][4]). Double-buffered LDS
// (96 KiB, 1 block/CU) with counted vmcnt (R5-verified skeleton).
//
// R6 change — INTERLEAVED K-step (R5 post-mortem: reads and MFMAs
// were phase-serial; LDS port idle during MFMA, MFMA pipe idle
// during reads; both structures pinned at ~820 TF). Now each 8-read
// fragment group overlaps a 16-MFMA cluster via register ping-pong:
//   read(cur,h1); lgkmcnt(8); MFMA(h0)        <- h1 reads fly under h0 MFMAs
//   lgkmcnt(0); barrier; STAGE(cur,kt+2)
//   vmcnt(6); barrier; read(nxt,h0); MFMA(h1) <- h0' reads fly under h1 MFMAs
// sched_barrier(0) after each counted wait (rule #18). setprio(1)
// around MFMA clusters (T5 — pays once phases have role-split).
//
// MODE 0: QKV proj, 768 blocks = 3 exact rounds, XCD-clustered.
// MODE 1: P~ = exp(QK^T/32 - 12) + rowsum. 512 blocks, 288 live.
// MODE 2: O = (P~ V)/rowsum; mtiles 5..7 split-K (halves -> P1 / raw
//         out, combine later), LPT order, 352 blocks, Vt XCD-local.
// ---------------------------------------------------------------
template <int MODE>
__global__ void __launch_bounds__(512) gemm_nt(
    const u16* __restrict__ xb, const u16* __restrict__ WqT,
    const u16* __restrict__ WkT, const u16* __restrict__ WvT,
    u16* __restrict__ Q, u16* __restrict__ Kb,
    u16* __restrict__ Vt, u16* __restrict__ S,
    float* __restrict__ rowsum, float* __restrict__ out,
    float* __restrict__ P1) {

    int mtile, ntile, z, kbeg = 0, kiters, kh = 2;
    const u16 *A, *B;

    if (MODE == 0) {
        int L = blockIdx.x;                      // 768 blocks
        int xcd = L & 7;
        int u = L >> 3;                          // 0..95
        z = u >> 5;                              // 0..2
        int v = u & 31;
        mtile = ((v >> 3) << 3) | xcd;           // 0..31, mtile&7==xcd
        ntile = v & 7;
        A = xb;
        B = (z == 0) ? WqT : (z == 1) ? WkT : WvT;
        kiters = 16;
    } else if (MODE == 1) {
        int L = blockIdx.x;                      // 512 blocks, 288 live
        z = L >> 7;
        int w = L & 127;
        mtile = w >> 4;                          // 0..7 (batch-local)
        ntile = w & 15;                          // 0..15
        if (ntile > 2 * mtile + 1) return;       // fully masked tile
        A = Q  + (size_t)z * (2048 * 1024);
        B = Kb + (size_t)z * (2048 * 1024);
        kiters = 16;
    } else {
        int L = blockIdx.x;                      // 352 blocks, LPT order
        ntile = L & 7;                           // Vt XCD-local
        z = (L >> 3) & 3;
        int ci = L >> 5;                         // 0..10
        mtile = cls2_m[ci];
        kh = cls2_h[ci];
        int half = 2 * (mtile + 1);              // BK64 units per half
        if (kh == 0)      { kbeg = 0;    kiters = half; }
        else if (kh == 1) { kbeg = half; kiters = half; }
        else              { kbeg = 0;    kiters = 4 * (mtile + 1); }
        A = S  + (size_t)z * (2048 * 2048);
        B = Vt + (size_t)z * (1024 * 2048);
    }

    const int LDA = (MODE == 2) ? 2048 : 1024;

    // LDS: A 2 bufs x 256x64 (32 KiB each), B 2 bufs x 128x64 (16 KiB)
    __shared__ __align__(16) u16 As[32768];
    __shared__ __align__(16) u16 Bs[16384 + MODE * 128];  // mode fingerprint

    const int tid  = threadIdx.x;
    const int lane = tid & 63;
    const int wave = tid >> 6;                   // 0..7
    const int wr = wave >> 1, wc = wave & 1;     // 4 x 2 wave grid

    // staging: 512 threads cover 128 rows x 4 swizzled 16B chunks / section
    const int r0 = tid >> 2;                     // 0..127
    const int kb = (((tid & 3) ^ ((r0 >> 1) & 3))) * 16;

    const char* gA0 = (const char*)(A + (size_t)(mtile * 256 +       r0) * LDA) + kb + kbeg * 128;
    const char* gA1 = (const char*)(A + (size_t)(mtile * 256 + 128 + r0) * LDA) + kb + kbeg * 128;
    const char* gB  = (const char*)(B + (size_t)(ntile * 128 +       r0) * LDA) + kb + kbeg * 128;

    auto STAGE = [&](int buf, int kt2) {
        const size_t off = (size_t)kt2 * 128;    // 64 K-elems * 2B
        char* a = (char*)As + buf * 32768 + tid * 16;
        char* b = (char*)Bs + buf * 16384 + tid * 16;
        load_lds16(gA0 + off,      a);
        load_lds16(gA0 + off + 64, a + 8192);
        load_lds16(gA1 + off,      a + 16384);
        load_lds16(gA1 + off + 64, a + 24576);
        load_lds16(gB  + off,      b);
        load_lds16(gB  + off + 64, b + 8192);
    };

    // read offsets (u16 units); de-swizzle identical to proven pattern
    const int quad = lane >> 4;
    const int l16  = lane & 15;
    const int ch   = quad ^ ((l16 >> 1) & 3);
    const int aoff = (wr >> 1) * 8192 + ((wr & 1) * 64 + l16) * 32 + ch * 8;
    const int boff = (wc * 64 + l16) * 32 + ch * 8;

    f32x4 acc[4][4] = {};
    bf16x8 afA[4], bvA[4], afB[4], bvB[4];       // ping-pong frag groups

    // prologue: stage tiles 0,1; wait tile0 only; pre-read (0,h0)
    STAGE(0, 0);
    STAGE(1, 1);
    asm volatile("s_waitcnt vmcnt(6)" ::: "memory");
    __builtin_amdgcn_s_barrier();
    {
        const u16* ap = As + aoff;
        const u16* bp = Bs + boff;
        #pragma unroll
        for (int r = 0; r < 4; ++r) afA[r] = *(const bf16x8*)(ap + r * 512);
        #pragma unroll
        for (int c = 0; c < 4; ++c) bvA[c] = *(const bf16x8*)(bp + c * 512);
    }

    int cur = 0;
    for (int kt = 0; kt < kiters; ++kt) {
        // ---- issue (cur,h1) reads; MFMA h0 overlaps them ----
        {
            const u16* ap = As + cur * 16384 + 4096 + aoff;
            const u16* bp = Bs + cur * 8192  + 4096 + boff;
            #pragma unroll
            for (int r = 0; r < 4; ++r) afB[r] = *(const bf16x8*)(ap + r * 512);
            #pragma unroll
            for (int c = 0; c < 4; ++c) bvB[c] = *(const bf16x8*)(bp + c * 512);
        }
        asm volatile("s_waitcnt lgkmcnt(8)" ::: "memory");  // h0 group landed
        __builtin_amdgcn_sched_barrier(0);
        __builtin_amdgcn_s_setprio(1);
        #pragma unroll
        for (int r = 0; r < 4; ++r)
            #pragma unroll
            for (int c = 0; c < 4; ++c)
                acc[r][c] = __builtin_amdgcn_mfma_f32_16x16x32_bf16(
                    afA[r], bvA[c], acc[r][c], 0, 0, 0);
        __builtin_amdgcn_s_setprio(0);
        asm volatile("s_waitcnt lgkmcnt(0)" ::: "memory");  // my reads of cur done
        __builtin_amdgcn_sched_barrier(0);
        __builtin_amdgcn_s_barrier();                        // buf cur free
        if (kt + 2 < kiters) STAGE(cur, kt + 2);
        if (kt + 1 < kiters) {
            // tile kt+1 (buf nxt) must be landed in all waves before reads
            if (kt + 2 < kiters) {
                asm volatile("s_waitcnt vmcnt(6)" ::: "memory");
            } else {
                asm volatile("s_waitcnt vmcnt(0)" ::: "memory");
            }
            __builtin_amdgcn_s_barrier();
            // ---- issue (nxt,h0) reads; MFMA h1 overlaps them ----
            const u16* ap = As + (cur ^ 1) * 16384 + aoff;
            const u16* bp = Bs + (cur ^ 1) * 8192  + boff;
            #pragma unroll
            for (int r = 0; r < 4; ++r) afA[r] = *(const bf16x8*)(ap + r * 512);
            #pragma unroll
            for (int c = 0; c < 4; ++c) bvA[c] = *(const bf16x8*)(bp + c * 512);
        }
        __builtin_amdgcn_s_setprio(1);
        #pragma unroll
        for (int r = 0; r < 4; ++r)
            #pragma unroll
            for (int c = 0; c < 4; ++c)
                acc[r][c] = __builtin_amdgcn_mfma_f32_16x16x32_bf16(
                    afB[r], bvB[c], acc[r][c], 0, 0, 0);
        __builtin_amdgcn_s_setprio(0);
        cur ^= 1;
    }

    // epilogue — C/D frag layout: col = l16, row = quad*4 + i
    const int grow0 = mtile * 256 + wr * 64 + quad * 4;
    const int gcol0 = ntile * 128 + wc * 64 + l16;

    if (MODE == 0) {
        if (z < 2) {
            u16* C = z ? Kb : Q;
            #pragma unroll
            for (int r = 0; r < 4; ++r)
                #pragma unroll
                for (int c = 0; c < 4; ++c)
                    #pragma unroll
                    for (int i = 0; i < 4; ++i)
                        C[(size_t)(grow0 + r * 16 + i) * 1024 + gcol0 + c * 16] =
                            f2bf(acc[r][c][i]);
        } else {
            // Vt[b][d][s]: m -> (b,s), n -> d; 4 consecutive i -> consecutive s
            #pragma unroll
            for (int r = 0; r < 4; ++r) {
                int m0 = grow0 + r * 16;
                int b = m0 >> 11, s0 = m0 & 2047;
                #pragma unroll
                for (int c = 0; c < 4; ++c) {
                    int d = gcol0 + c * 16;
                    ushort4 o;
                    o.x = f2bf(acc[r][c][0]); o.y = f2bf(acc[r][c][1]);
                    o.z = f2bf(acc[r][c][2]); o.w = f2bf(acc[r][c][3]);
                    *(ushort4*)(Vt + (size_t)b * (1024 * 2048) + (size_t)d * 2048 + s0) = o;
                }
            }
        }
    } else if (MODE == 1) {
        u16* C = S + (size_t)z * (2048 * 2048);
        float* rs = rowsum + z * 2048;
        const bool maskchk = (ntile >= 2 * mtile);   // tile straddles diagonal
        float rsum[4][4];
        #pragma unroll
        for (int r = 0; r < 4; ++r)
            #pragma unroll
            for (int i = 0; i < 4; ++i) rsum[r][i] = 0.f;
        #pragma unroll
        for (int r = 0; r < 4; ++r)
            #pragma unroll
            for (int c = 0; c < 4; ++c)
                #pragma unroll
                for (int i = 0; i < 4; ++i) {
                    int grow = grow0 + r * 16 + i;
                    int gcol = gcol0 + c * 16;
                    float e = 0.f;
                    if (!maskchk || gcol <= grow)
                        e = __expf(acc[r][c][i] * 0.03125f - 12.0f);
                    C[(size_t)grow * 2048 + gcol] = f2bf(e);
                    rsum[r][i] += e;
                }
        #pragma unroll
        for (int r = 0; r < 4; ++r)
            #pragma unroll
            for (int i = 0; i < 4; ++i) {
                float s = rsum[r][i];
                s += __shfl_xor(s, 1, 64);
                s += __shfl_xor(s, 2, 64);
                s += __shfl_xor(s, 4, 64);
                s += __shfl_xor(s, 8, 64);
                if (l16 == 0)
                    unsafeAtomicAdd(&rs[grow0 + r * 16 + i], s);
            }
    } else {  // MODE 2
        if (kh == 2) {
            const float* rs = rowsum + z * 2048;
            float* C = out + (size_t)z * (2048 * 1024);
            #pragma unroll
            for (int r = 0; r < 4; ++r)
                #pragma unroll
                for (int i = 0; i < 4; ++i) {
                    int grow = grow0 + r * 16 + i;
                    float inv = 1.0f / rs[grow];
                    #pragma unroll
                    for (int c = 0; c < 4; ++c)
                        C[(size_t)grow * 1024 + gcol0 + c * 16] = acc[r][c][i] * inv;
                }
        } else if (kh == 1) {
            // raw partial straight into out (combined+normalized later)
            float* C = out + (size_t)z * (2048 * 1024);
            #pragma unroll
            for (int r = 0; r < 4; ++r)
                #pragma unroll
                for (int i = 0; i < 4; ++i) {
                    int grow = grow0 + r * 16 + i;
                    #pragma unroll
                    for (int c = 0; c < 4; ++c)
                        C[(size_t)grow * 1024 + gcol0 + c * 16] = acc[r][c][i];
                }
        } else {
            // raw partial into P1 (rows 1280..2047 -> 0..767)
            float* Pp = P1 + (size_t)z * (768 * 1024);
            #pragma unroll
            for (int r = 0; r < 4; ++r)
                #pragma unroll
                for (int i = 0; i < 4; ++i) {
                    int prow = grow0 + r * 16 + i - 1280;
                    #pragma unroll
                    for (int c = 0; c < 4; ++c)
                        Pp[(size_t)prow * 1024 + gcol0 + c * 16] = acc[r][c][i];
                }
        }
    }
}

// ---------------------------------------------------------------
// launch
// ---------------------------------------------------------------
extern "C" void kernel_launch(void* const* d_in, const int* in_sizes, int n_in,
                              void* d_out, int out_size, void* d_ws, size_t ws_size,
                              hipStream_t stream) {
    const float* x  = (const float*)d_in[0];
    const float* Wq = (const float*)d_in[1];
    const float* Wk = (const float*)d_in[2];
    const float* Wv = (const float*)d_in[3];
    float* out = (float*)d_out;
    char* ws = (char*)d_ws;
    const size_t Mi = 1u << 20;

    u16* xb  = (u16*)(ws);               // [8192][1024] bf16  16 MiB
    u16* WqT = (u16*)(ws + 16 * Mi);     // [1024][1024] bf16   2 MiB
    u16* WkT = (u16*)(ws + 18 * Mi);
    u16* WvT = (u16*)(ws + 20 * Mi);
    u16* Q   = (u16*)(ws + 22 * Mi);     // [8192][1024] bf16  16 MiB
    u16* Kb  = (u16*)(ws + 38 * Mi);
    u16* Vt  = (u16*)(ws + 54 * Mi);     // [4][1024][2048] bf16 16 MiB
    u16* S   = (u16*)(ws + 70 * Mi);     // [4][2048][2048] bf16 32 MiB (P~)
    float* rowsum = (float*)(ws + 102 * Mi);  // [4][2048] fp32
    float* P1 = (float*)xb;              // split-K partials reuse dead xb (12 MiB used)

    // prep: cast x + transpose W + zero rowsum
    prep_kernel<<<11296, 256, 0, stream>>>(
        (const float4*)x, xb, Wq, Wk, Wv, WqT, WkT, WvT, rowsum);

    // QKV projections (z: 0=Q, 1=K, 2=Vt) — 3 exact rounds at 1 block/CU
    gemm_nt<0><<<768, 512, 0, stream>>>(xb, WqT, WkT, WvT, Q, Kb, Vt, S, rowsum, out, P1);

    // P~ = exp(QK^T/32 - 12) + rowsum, live causal tiles
    gemm_nt<1><<<512, 512, 0, stream>>>(xb, WqT, WkT, WvT, Q, Kb, Vt, S, rowsum, out, P1);

    // O = (P~ V)/rowsum; mtiles 5..7 split-K, LPT order, Vt XCD-local
    gemm_nt<2><<<352, 512, 0, stream>>>(xb, WqT, WkT, WvT, Q, Kb, Vt, S, rowsum, out, P1);

    // merge + normalize split-K rows (1280..2047 per batch)
    combine_kernel<<<3072, 256, 0, stream>>>(
        (const float4*)P1, rowsum, (float4*)out);
}

// Round 9
// 222.945 us; speedup vs baseline: 1.1261x; 1.1261x over previous
//
#include <hip/hip_runtime.h>

typedef unsigned short u16;
typedef __bf16 bf16x8 __attribute__((ext_vector_type(8)));
typedef float f32x4 __attribute__((ext_vector_type(4)));

// ---------- bf16 <-> f32 helpers (RNE) ----------
__device__ __forceinline__ u16 f2bf(float f) {
    union { float f; unsigned int u; } v; v.f = f;
    unsigned int u = v.u;
    return (u16)((u + 0x7FFFu + ((u >> 16) & 1u)) >> 16);
}

// ---------- async global->LDS, 16B per lane ----------
__device__ __forceinline__ void load_lds16(const void* g, void* l) {
    __builtin_amdgcn_global_load_lds(
        (const __attribute__((address_space(1))) unsigned int*)g,
        (__attribute__((address_space(3))) unsigned int*)l,
        16, 0, 0);
}

// MODE2 classes, LPT (heaviest-first). Work in BK64 K-tiles at 256x256:
// full tiles m<4: 4(m+1); split halves m>=4: 2(m+1) each. kh==2 -> full.
// Desc: m7h(16) m7h(16) m3f(16) m6h(14) m6h(14) m5h(12) m5h(12) m2f(12)
//       m4h(10) m4h(10) m1f(8) m0f(4)
__constant__ unsigned char c2m[12] = {7,7,3,6,6,5,5,2,4,4,1,0};
__constant__ unsigned char c2h[12] = {0,1,2,0,1,0,1,2,0,1,2,2};

// ---------------------------------------------------------------
// fused prep: 0..8191 cast x fp32->bf16; 8192..11263 transpose W;
// 11264..11295 zero rowsum (8192 floats).
// ---------------------------------------------------------------
__global__ void __launch_bounds__(256) prep_kernel(
    const float4* __restrict__ X, u16* __restrict__ xb,
    const float* __restrict__ Wq, const float* __restrict__ Wk,
    const float* __restrict__ Wv,
    u16* __restrict__ Oq, u16* __restrict__ Ok, u16* __restrict__ Ov,
    float* __restrict__ rowsum) {
    __shared__ float tile[32][33];
    const int bid = blockIdx.x, tid = threadIdx.x;
    if (bid < 8192) {
        int idx = bid * 256 + tid;
        float4 v = X[idx];
        ushort4 o;
        o.x = f2bf(v.x); o.y = f2bf(v.y); o.z = f2bf(v.z); o.w = f2bf(v.w);
        *(ushort4*)(xb + (size_t)idx * 4) = o;
    } else if (bid < 11264) {
        int id = bid - 8192;
        int zz = id >> 10;
        const float* W = (zz == 0) ? Wq : (zz == 1) ? Wk : Wv;
        u16* O = (zz == 0) ? Oq : (zz == 1) ? Ok : Ov;
        int n0 = (id & 31) * 32, k0 = ((id >> 5) & 31) * 32;
        int tx = tid & 31, ty = tid >> 5;
        #pragma unroll
        for (int j = 0; j < 32; j += 8)
            tile[ty + j][tx] = W[(size_t)(k0 + ty + j) * 1024 + n0 + tx];
        __syncthreads();
        #pragma unroll
        for (int j = 0; j < 32; j += 8)
            O[(size_t)(n0 + ty + j) * 1024 + k0 + tx] = f2bf(tile[tx][ty + j]);
    } else {
        rowsum[(bid - 11264) * 256 + tid] = 0.f;
    }
}

// ---------------------------------------------------------------
// combine: out[z][1024+r][:] = (out + P1) * inv(rowsum) for the
// MODE2 split-K rows (m 4..7 -> rows 1024..2047 per batch).
// ---------------------------------------------------------------
__global__ void __launch_bounds__(256) combine_kernel(
    const float4* __restrict__ P1, const float* __restrict__ rowsum,
    float4* __restrict__ out) {
    int b = blockIdx.x;                        // 0..4095
    int z = b >> 10;
    int i = (b & 1023) * 256 + threadIdx.x;    // 0..262143 float4 within z
    int r = i >> 8;                            // 256 float4 per row
    float inv = 1.0f / rowsum[z * 2048 + 1024 + r];
    size_t oi = (size_t)z * (2048 * 1024 / 4) + (1024 * 1024 / 4) + i;
    float4 a = out[oi];
    float4 p = P1[(size_t)z * (1024 * 1024 / 4) + i];
    a.x = (a.x + p.x) * inv;
    a.y = (a.y + p.y) * inv;
    a.z = (a.z + p.z) * inv;
    a.w = (a.w + p.w) * inv;
    out[oi] = a;
}

// ---------------------------------------------------------------
// R0-VERBATIM proven QKV kernel: NT bf16 GEMM, 128x128 tile, 512
// threads = 8 waves 2x4, BK=64 single-buffer, 2 blocks/CU (the
// measured-820TF regime via cross-block overlap). Unchanged.
// ---------------------------------------------------------------
__global__ void __launch_bounds__(512) gemm_qkv(
    const u16* __restrict__ xb, const u16* __restrict__ WqT,
    const u16* __restrict__ WkT, const u16* __restrict__ WvT,
    u16* __restrict__ Q, u16* __restrict__ Kb, u16* __restrict__ Vt) {

    int L = blockIdx.x;                       // 1536 blocks
    int c = L & 7, t = (L >> 3) & 7, hi = L >> 6;
    int p = hi * 8 + c;                       // 0..191; mtile&7 == c
    int z = p >> 6, mtile = p & 63, ntile = t;
    const u16* A = xb;
    const u16* B = (z == 0) ? WqT : (z == 1) ? WkT : WvT;

    __shared__ __align__(16) u16 As[128 * 64];
    __shared__ __align__(16) u16 Bs[128 * 64];

    const int tid = threadIdx.x;
    const int lane = tid & 63;
    const int wave = tid >> 6;
    const int wr = wave >> 2, wc = wave & 3;

    const int r0 = tid >> 2;
    const int kb = (((tid & 3) ^ ((r0 >> 1) & 3))) * 16;

    const char* gA = (const char*)(A + (size_t)(mtile * 128 + r0) * 1024) + kb;
    const char* gB = (const char*)(B + (size_t)(ntile * 128 + r0) * 1024) + kb;

    char* lA = (char*)As + tid * 16;
    char* lB = (char*)Bs + tid * 16;

    f32x4 acc[4][2] = {};

    const int quad = lane >> 4;
    const int l16 = lane & 15;
    const int ch = quad ^ ((l16 >> 1) & 3);
    const int aoff = (wr * 64 + l16) * 32 + ch * 8;
    const int boff = (wc * 32 + l16) * 32 + ch * 8;

    for (int kt = 0; kt < 16; ++kt) {
        load_lds16(gA,      lA);
        load_lds16(gA + 64, lA + 8192);
        load_lds16(gB,      lB);
        load_lds16(gB + 64, lB + 8192);
        gA += 128; gB += 128;
        __syncthreads();

        #pragma unroll
        for (int h = 0; h < 2; ++h) {
            const u16* ap = As + h * 4096 + aoff;
            const u16* bp = Bs + h * 4096 + boff;
            bf16x8 af[4], bfv[2];
            #pragma unroll
            for (int r = 0; r < 4; ++r) af[r] = *(const bf16x8*)(ap + r * 512);
            #pragma unroll
            for (int cc = 0; cc < 2; ++cc) bfv[cc] = *(const bf16x8*)(bp + cc * 512);
            #pragma unroll
            for (int r = 0; r < 4; ++r)
                #pragma unroll
                for (int cc = 0; cc < 2; ++cc)
                    acc[r][cc] = __builtin_amdgcn_mfma_f32_16x16x32_bf16(
                        af[r], bfv[cc], acc[r][cc], 0, 0, 0);
        }
        __syncthreads();
    }

    const int grow0 = mtile * 128 + wr * 64 + quad * 4;
    const int gcol0 = ntile * 128 + wc * 32 + l16;

    if (z < 2) {
        u16* C = z ? Kb : Q;
        #pragma unroll
        for (int r = 0; r < 4; ++r)
            #pragma unroll
            for (int cc = 0; cc < 2; ++cc)
                #pragma unroll
                for (int i = 0; i < 4; ++i)
                    C[(size_t)(grow0 + r * 16 + i) * 1024 + gcol0 + cc * 16] =
                        f2bf(acc[r][cc][i]);
    } else {
        #pragma unroll
        for (int r = 0; r < 4; ++r) {
            int m0 = grow0 + r * 16;
            int b = m0 >> 11, s0 = m0 & 2047;
            #pragma unroll
            for (int cc = 0; cc < 2; ++cc) {
                int d = gcol0 + cc * 16;
                ushort4 o;
                o.x = f2bf(acc[r][cc][0]); o.y = f2bf(acc[r][cc][1]);
                o.z = f2bf(acc[r][cc][2]); o.w = f2bf(acc[r][cc][3]);
                *(ushort4*)(Vt + (size_t)b * (1024 * 2048) + (size_t)d * 2048 + s0) = o;
            }
        }
    }
}

// ---------------------------------------------------------------
// 8-PHASE 256x256 template port (m201 structure, plain HIP).
// BK=64, 512 threads = 8 waves (2M x 4N), per-wave C = 128x64 =
// acc[8][4] f32x4. LDS 128 KiB = 2 tile-buffers x (A 32K + B 32K),
// each array staged as 2 "halves" matching quadrant unions:
//   A-h0 = rows {0-63,128-191}, A-h1 = {64-127,192-255}
//   B-h0 = cols {0-31,64-95,128-159,192-223}, B-h1 = +32
// 4 phases per K-tile u = 4 C-quadrants in order (m0n0)(m0n1)(m1n1)(m1n0);
// phase p stages ONE half (2 global_load_lds) into the region freed by
// phase p-1: ph1->B-h0(u+1) [other buf], ph2->A-h0(u+2), ph3->B-h1(u+2),
// ph4->A-h1(u+2) [current buf, region just consumed]. vmcnt(6) ONLY at
// ph4: confirms all but the 3 newest pairs == next tile fully landed
// (its B-h0 is the 4th-newest pair). Never drains in-loop. Each phase:
// reads+stage -> barrier -> setprio(1) 16 MFMA setprio(0) -> barrier.
// Per-8KiB-section layout/XOR-chunk swizzle is the R0-measured
// 0-bank-conflict pattern (stage-source and read use the same involution).
//
// MODE 1: Ptilde = exp(QK^T/32 - 12) into S + rowsum. 256 blocks,
//         144 live (ntile<=mtile), single round on 256 CUs.
// MODE 2: O = Ptilde V; m<4 full (normalized), m>=4 split-K halves
//         (kh0 -> P1 raw, kh1 -> out raw), LPT order, 192 blocks.
// ---------------------------------------------------------------
template <int MODE>
__global__ void __launch_bounds__(512) gemm8(
    const u16* __restrict__ Q, const u16* __restrict__ Kb,
    const u16* __restrict__ Vt, u16* __restrict__ S,
    float* __restrict__ rowsum, float* __restrict__ out,
    float* __restrict__ P1) {

    int mtile, ntile, z, kbeg = 0, nt, kh = 2;
    const u16 *A, *B;
    int LDA;

    if (MODE == 1) {
        int L = blockIdx.x;                    // 256 blocks, 144 live
        z = L >> 6;
        int w = L & 63;
        mtile = w >> 3; ntile = w & 7;
        if (ntile > mtile) return;             // above diagonal: dead
        A = Q  + (size_t)z * (2048 * 1024);
        B = Kb + (size_t)z * (2048 * 1024);
        nt = 16; LDA = 1024;
    } else {
        int L = blockIdx.x;                    // 192 blocks, LPT order
        ntile = L & 3;
        z = (L >> 2) & 3;
        int ci = L >> 4;                       // 0..11
        mtile = c2m[ci]; kh = c2h[ci];
        int half = 2 * (mtile + 1);
        if (kh == 0)      { kbeg = 0;    nt = half; }
        else if (kh == 1) { kbeg = half; nt = half; }
        else              { kbeg = 0;    nt = 4 * (mtile + 1); }
        A = S  + (size_t)z * (2048 * 2048);
        B = Vt + (size_t)z * (1024 * 2048);
        LDA = 2048;
    }

    __shared__ __align__(16) char LDSc[131072];   // 2 bufs x 64 KiB

    const int tid  = threadIdx.x;
    const int lane = tid & 63;
    const int wave = tid >> 6;
    const int wr = wave >> 2;                  // 0..1  (M)
    const int wc = wave & 3;                   // 0..3  (N)
    const int quad = lane >> 4, l16 = lane & 15;
    const int ch = quad ^ ((l16 >> 1) & 3);

    // ---- staging source addresses (per-lane, swizzled chunk) ----
    const int sl = tid >> 2;                                  // LDS row 0..127
    const int sc = ((tid & 3) ^ ((sl >> 1) & 3)) * 16;        // swizzled 16B chunk
    const int gAr = mtile * 256 + (sl & 63) + ((sl >> 6) << 7);   // A-h0 row
    const int gBr = ntile * 256 + (sl & 31) + ((sl >> 5) << 6);   // B-h0 row
    const char* gp0 = (const char*)(A + (size_t)gAr * LDA) + sc + kbeg * 128;        // A-h0
    const char* gp1 = (const char*)(A + (size_t)(gAr + 64) * LDA) + sc + kbeg * 128; // A-h1
    const char* gp2 = (const char*)(B + (size_t)gBr * LDA) + sc + kbeg * 128;        // B-h0
    const char* gp3 = (const char*)(B + (size_t)(gBr + 32) * LDA) + sc + kbeg * 128; // B-h1

    // kind: 0=A-h0(+0) 1=A-h1(+16K) 2=B-h0(+32K) 3=B-h1(+48K); buf(t)=t&1
#define STG(kind, gp, t) do { \
        char* lb_ = LDSc + (((t) & 1) << 16) + ((kind) << 14) + tid * 16; \
        const char* g_ = (gp) + (size_t)(t) * 128; \
        load_lds16(g_,      lb_); \
        load_lds16(g_ + 64, lb_ + 8192); } while (0)

    // ---- read base offsets (bytes within a buffer) ----
    const int aBase = (wr * 64 + l16) * 64 + ch * 16;           // + m*16384 + k*8192 + a*1024
    const int bBase = 32768 + (wc * 32 + l16) * 64 + ch * 16;   // + n*16384 + k*8192 + f*1024

    f32x4 acc[8][4] = {};
    bf16x8 af[4][2], b0[2][2], b1[2][2];

    // ---- prologue: tile0 full + tile1 all-but-B-h0; confirm tile0 ----
    STG(0, gp0, 0); STG(2, gp2, 0); STG(1, gp1, 0); STG(3, gp3, 0);
    if (nt > 1) { STG(0, gp0, 1); STG(3, gp3, 1); STG(1, gp1, 1); }
    if (nt > 1) asm volatile("s_waitcnt vmcnt(6)" ::: "memory");
    else        asm volatile("s_waitcnt vmcnt(0)" ::: "memory");
    __builtin_amdgcn_s_barrier();
    __builtin_amdgcn_sched_barrier(0);

    for (int u = 0; u < nt; ++u) {
        const int bo = (u & 1) << 16;
        // ======== phase 1: quadrant (m0, n0) ========
        #pragma unroll
        for (int a = 0; a < 4; ++a)
            #pragma unroll
            for (int k = 0; k < 2; ++k)
                af[a][k] = *(const bf16x8*)(LDSc + bo + k * 8192 + a * 1024 + aBase);
        #pragma unroll
        for (int f = 0; f < 2; ++f)
            #pragma unroll
            for (int k = 0; k < 2; ++k)
                b0[f][k] = *(const bf16x8*)(LDSc + bo + k * 8192 + f * 1024 + bBase);
        if (u + 1 < nt) STG(2, gp2, u + 1);
        __builtin_amdgcn_s_barrier();
        __builtin_amdgcn_s_setprio(1);
        #pragma unroll
        for (int k = 0; k < 2; ++k)
            #pragma unroll
            for (int a = 0; a < 4; ++a)
                #pragma unroll
                for (int f = 0; f < 2; ++f)
                    acc[a][f] = __builtin_amdgcn_mfma_f32_16x16x32_bf16(
                        af[a][k], b0[f][k], acc[a][f], 0, 0, 0);
        __builtin_amdgcn_s_setprio(0);
        __builtin_amdgcn_s_barrier();
        __builtin_amdgcn_sched_barrier(0);
        // ======== phase 2: quadrant (m0, n1) ========
        #pragma unroll
        for (int f = 0; f < 2; ++f)
            #pragma unroll
            for (int k = 0; k < 2; ++k)
                b1[f][k] = *(const bf16x8*)(LDSc + bo + 16384 + k * 8192 + f * 1024 + bBase);
        if (u + 2 < nt) STG(0, gp0, u + 2);
        __builtin_amdgcn_s_barrier();
        __builtin_amdgcn_s_setprio(1);
        #pragma unroll
        for (int k = 0; k < 2; ++k)
            #pragma unroll
            for (int a = 0; a < 4; ++a)
                #pragma unroll
                for (int f = 0; f < 2; ++f)
                    acc[a][2 + f] = __builtin_amdgcn_mfma_f32_16x16x32_bf16(
                        af[a][k], b1[f][k], acc[a][2 + f], 0, 0, 0);
        __builtin_amdgcn_s_setprio(0);
        __builtin_amdgcn_s_barrier();
        __builtin_amdgcn_sched_barrier(0);
        // ======== phase 3: quadrant (m1, n1) ========
        #pragma unroll
        for (int a = 0; a < 4; ++a)
            #pragma unroll
            for (int k = 0; k < 2; ++k)
                af[a][k] = *(const bf16x8*)(LDSc + bo + 16384 + k * 8192 + a * 1024 + aBase);
        if (u + 2 < nt) STG(3, gp3, u + 2);
        __builtin_amdgcn_s_barrier();
        __builtin_amdgcn_s_setprio(1);
        #pragma unroll
        for (int k = 0; k < 2; ++k)
            #pragma unroll
            for (int a = 0; a < 4; ++a)
                #pragma unroll
                for (int f = 0; f < 2; ++f)
                    acc[4 + a][2 + f] = __builtin_amdgcn_mfma_f32_16x16x32_bf16(
                        af[a][k], b1[f][k], acc[4 + a][2 + f], 0, 0, 0);
        __builtin_amdgcn_s_setprio(0);
        __builtin_amdgcn_s_barrier();
        __builtin_amdgcn_sched_barrier(0);
        // ======== phase 4: quadrant (m1, n0) ========
        #pragma unroll
        for (int f = 0; f < 2; ++f)
            #pragma unroll
            for (int k = 0; k < 2; ++k)
                b0[f][k] = *(const bf16x8*)(LDSc + bo + k * 8192 + f * 1024 + bBase);
        if (u + 2 < nt) STG(1, gp1, u + 2);
        __builtin_amdgcn_s_barrier();
        __builtin_amdgcn_s_setprio(1);
        #pragma unroll
        for (int k = 0; k < 2; ++k)
            #pragma unroll
            for (int a = 0; a < 4; ++a)
                #pragma unroll
                for (int f = 0; f < 2; ++f)
                    acc[4 + a][f] = __builtin_amdgcn_mfma_f32_16x16x32_bf16(
                        af[a][k], b0[f][k], acc[4 + a][f], 0, 0, 0);
        __builtin_amdgcn_s_setprio(0);
        if (u + 2 < nt)      asm volatile("s_waitcnt vmcnt(6)" ::: "memory");
        else if (u + 1 < nt) asm volatile("s_waitcnt vmcnt(0)" ::: "memory");
        __builtin_amdgcn_s_barrier();
        __builtin_amdgcn_sched_barrier(0);
    }
#undef STG

    // ---- epilogue: frag (ar, c): row = mtile*256 + wr*128 + (ar>>2)*64
    //      + (ar&3)*16 + quad*4 + i ; col = ntile*256 + wc*64 + c*16 + l16
    const int rb = mtile * 256 + wr * 128 + quad * 4;
    const int cb = ntile * 256 + wc * 64 + l16;

    if (MODE == 1) {
        u16* C = S + (size_t)z * (2048 * 2048);
        float* rs = rowsum + z * 2048;
        const bool diag = (ntile == mtile);
        #pragma unroll
        for (int ar = 0; ar < 8; ++ar)
            #pragma unroll
            for (int i = 0; i < 4; ++i) {
                int grow = rb + (ar >> 2) * 64 + (ar & 3) * 16 + i;
                float rsum = 0.f;
                #pragma unroll
                for (int c = 0; c < 4; ++c) {
                    int gcol = cb + c * 16;
                    float e = 0.f;
                    if (!diag || gcol <= grow)
                        e = __expf(acc[ar][c][i] * 0.03125f - 12.0f);
                    C[(size_t)grow * 2048 + gcol] = f2bf(e);
                    rsum += e;
                }
                rsum += __shfl_xor(rsum, 1, 64);
                rsum += __shfl_xor(rsum, 2, 64);
                rsum += __shfl_xor(rsum, 4, 64);
                rsum += __shfl_xor(rsum, 8, 64);
                if (l16 == 0)
                    unsafeAtomicAdd(&rs[grow], rsum);
            }
    } else {
        if (kh == 2) {
            const float* rs = rowsum + z * 2048;
            float* C = out + (size_t)z * (2048 * 1024);
            #pragma unroll
            for (int ar = 0; ar < 8; ++ar)
                #pragma unroll
                for (int i = 0; i < 4; ++i) {
                    int grow = rb + (ar >> 2) * 64 + (ar & 3) * 16 + i;
                    float inv = 1.0f / rs[grow];
                    #pragma unroll
                    for (int c = 0; c < 4; ++c)
                        C[(size_t)grow * 1024 + cb + c * 16] = acc[ar][c][i] * inv;
                }
        } else if (kh == 1) {
            float* C = out + (size_t)z * (2048 * 1024);
            #pragma unroll
            for (int ar = 0; ar < 8; ++ar)
                #pragma unroll
                for (int i = 0; i < 4; ++i) {
                    int grow = rb + (ar >> 2) * 64 + (ar & 3) * 16 + i;
                    #pragma unroll
                    for (int c = 0; c < 4; ++c)
                        C[(size_t)grow * 1024 + cb + c * 16] = acc[ar][c][i];
                }
        } else {
            float* Pp = P1 + (size_t)z * (1024 * 1024);
            #pragma unroll
            for (int ar = 0; ar < 8; ++ar)
                #pragma unroll
                for (int i = 0; i < 4; ++i) {
                    int prow = rb + (ar >> 2) * 64 + (ar & 3) * 16 + i - 1024;
                    #pragma unroll
                    for (int c = 0; c < 4; ++c)
                        Pp[(size_t)prow * 1024 + cb + c * 16] = acc[ar][c][i];
                }
        }
    }
}

// ---------------------------------------------------------------
// launch
// ---------------------------------------------------------------
extern "C" void kernel_launch(void* const* d_in, const int* in_sizes, int n_in,
                              void* d_out, int out_size, void* d_ws, size_t ws_size,
                              hipStream_t stream) {
    const float* x  = (const float*)d_in[0];
    const float* Wq = (const float*)d_in[1];
    const float* Wk = (const float*)d_in[2];
    const float* Wv = (const float*)d_in[3];
    float* out = (float*)d_out;
    char* ws = (char*)d_ws;
    const size_t Mi = 1u << 20;

    u16* xb  = (u16*)(ws);               // [8192][1024] bf16  16 MiB
    u16* WqT = (u16*)(ws + 16 * Mi);     // [1024][1024] bf16   2 MiB
    u16* WkT = (u16*)(ws + 18 * Mi);
    u16* WvT = (u16*)(ws + 20 * Mi);
    u16* Q   = (u16*)(ws + 22 * Mi);     // [8192][1024] bf16  16 MiB
    u16* Kb  = (u16*)(ws + 38 * Mi);
    u16* Vt  = (u16*)(ws + 54 * Mi);     // [4][1024][2048] bf16 16 MiB
    u16* S   = (u16*)(ws + 70 * Mi);     // [4][2048][2048] bf16 32 MiB (P~)
    float* rowsum = (float*)(ws + 102 * Mi);  // [4][2048] fp32
    float* P1 = (float*)xb;              // split-K partials reuse dead xb (16 MiB)

    // prep: cast x + transpose W + zero rowsum
    prep_kernel<<<11296, 256, 0, stream>>>(
        (const float4*)x, xb, Wq, Wk, Wv, WqT, WkT, WvT, rowsum);

    // QKV projections — R0-proven 128x128 kernel, 3 exact rounds
    gemm_qkv<<<1536, 512, 0, stream>>>(xb, WqT, WkT, WvT, Q, Kb, Vt);

    // Ptilde = exp(QK^T/32 - 12) + rowsum — 8-phase 256x256, single round
    gemm8<1><<<256, 512, 0, stream>>>(Q, Kb, Vt, S, rowsum, out, P1);

    // O = Ptilde V — 8-phase 256x256, split-K m>=4, LPT order
    gemm8<2><<<192, 512, 0, stream>>>(Q, Kb, Vt, S, rowsum, out, P1);

    // merge + normalize split-K rows (1024..2047 per batch)
    combine_kernel<<<4096, 256, 0, stream>>>(
        (const float4*)P1, rowsum, (float4*)out);
}